// Round 11
// baseline (343.636 us; speedup 1.0000x reference)
//
#include <hip/hip_runtime.h>
#include <math.h>

#define NSC 64
#define NVC 64
#define EMB 32
#define NTYPES 20
#define NB 8
#define RH 16
#define LAYERS 2
#define CUTV 3.5f
#define HSTEP 0.1f

// ---------------------------------------------------------------------------
// Exact LAPACK-style Householder QR of Ku^T (64x2) -> Q (64x2), wave-parallel.
// ---------------------------------------------------------------------------
__device__ __forceinline__ float wave_sum(float t)
{
  #pragma unroll
  for (int mm = 1; mm < 64; mm <<= 1) t += __shfl_xor(t, mm, 64);
  return t;
}

__global__ void qr_kernel(const float* __restrict__ Ku, float* __restrict__ Q)
{
  const int i = threadIdx.x;  // 64 lanes
  float a0 = Ku[i], a1 = Ku[64 + i];
  const float xn2 = wave_sum((i >= 1) ? a0 * a0 : 0.f);
  const float alpha = __shfl(a0, 0, 64);
  const float beta0 = -copysignf(sqrtf(alpha * alpha + xn2), alpha);
  const float tau0 = (beta0 - alpha) / beta0;
  const float inv0 = 1.f / (alpha - beta0);
  const float v0 = (i == 0) ? 1.f : a0 * inv0;
  const float w = wave_sum(v0 * a1);
  a1 -= tau0 * w * v0;
  const float alpha1 = __shfl(a1, 1, 64);
  const float xn2b = wave_sum((i >= 2) ? a1 * a1 : 0.f);
  const float beta1 = -copysignf(sqrtf(alpha1 * alpha1 + xn2b), alpha1);
  const float tau1 = (beta1 - alpha1) / beta1;
  const float inv1 = 1.f / (alpha1 - beta1);
  const float v1 = (i == 0) ? 0.f : ((i == 1) ? 1.f : a1 * inv1);
  const float t1v = ((i == 1) ? 1.f : 0.f) - tau1 * v1;
  const float d = wave_sum(v0 * t1v);
  Q[i * 2 + 0] = ((i == 0) ? 1.f : 0.f) - tau0 * v0;
  Q[i * 2 + 1] = t1v - tau0 * d * v0;
}

// ---------------------------------------------------------------------------
// State layout: st4[node*64+lane] = (s, vx, vy, vz) — one float4 per (node,ch).
// ---------------------------------------------------------------------------
__global__ void init_state(const float* __restrict__ x, const float* __restrict__ Qm,
                           float4* __restrict__ st0, int* __restrict__ cnt, int n)
{
  const int i = blockIdx.x * 256 + threadIdx.x;
  const int node = i >> 6, lane = i & 63;
  if (node < n) {
    const float q0 = Qm[lane * 2 + 0], q1 = Qm[lane * 2 + 1];
    const float* xp = x + (size_t)node * 6;
    st0[i] = make_float4(0.f,
                         xp[0] * q0 + xp[3] * q1,
                         xp[1] * q0 + xp[4] * q1,
                         xp[2] * q0 + xp[5] * q1);
  }
  if (i < n) cnt[i] = 0;
}

__global__ void hist_kernel(const int* __restrict__ edst, int* __restrict__ cnt, int m)
{
  const int e = blockIdx.x * 256 + threadIdx.x;
  if (e < m) atomicAdd(&cnt[edst[e]], 1);
}

// Single-block exclusive scan of counts.
__global__ void scan_kernel(int* cnt, int* off, int n)
{
  __shared__ int lds[1024];
  const int t = threadIdx.x;
  const int CH = (n + 1023) >> 10;
  const int base = t * CH;
  int local[16];
  int run = 0;
  for (int j = 0; j < CH; ++j) {
    int v = (base + j < n) ? cnt[base + j] : 0;
    local[j] = run;
    run += v;
  }
  lds[t] = run;
  __syncthreads();
  for (int s = 1; s < 1024; s <<= 1) {
    int v = (t >= s) ? lds[t - s] : 0;
    __syncthreads();
    lds[t] += v;
    __syncthreads();
  }
  const int excl = lds[t] - run;
  for (int j = 0; j < CH; ++j) {
    if (base + j < n) {
      int o = excl + local[j];
      off[base + j] = o;
      cnt[base + j] = o;
    }
  }
  if (t == 1023) off[n] = lds[1023];
}

__global__ void scatter_kernel(const int* __restrict__ edst, int* __restrict__ cursor,
                               int* __restrict__ csr, int m)
{
  const int e = blockIdx.x * 256 + threadIdx.x;
  if (e < m) {
    int p = atomicAdd(&cursor[edst[e]], 1);
    csr[p] = e;
  }
}

// Edge arrays in CSR (destination-sorted) order — computed once.
__global__ void reorder_kernel(const int* __restrict__ csr,
                               const int* __restrict__ esrc, const int* __restrict__ edst,
                               int* __restrict__ esrc_s, int* __restrict__ edst_s, int m)
{
  const int k = blockIdx.x * 256 + threadIdx.x;
  if (k < m) {
    const int e = csr[k];
    esrc_s[k] = esrc[e];
    edst_s[k] = edst[e];
  }
}

// ---------------------------------------------------------------------------
// Per-(layer,type) folded self-connection weights, output-parallel.
// ---------------------------------------------------------------------------
__global__ void type_weights(const float* __restrict__ embed,
                             const float* __restrict__ Wss,
                             const float* __restrict__ Wsv,
                             float* __restrict__ Ws, float* __restrict__ Wv,
                             int total_s, int total_v)
{
  const int i = blockIdx.x * 256 + threadIdx.x;
  if (i < total_s) {
    const int bid = i >> 13;
    const int p = i & 8191;
    const int l = bid / NTYPES, t = bid % NTYPES;
    const int s = p >> 7, o = p & 127;
    const float* ar = embed + t * EMB;
    const float* wp = Wss + ((size_t)(l * 64 + s) * EMB) * 128 + o;
    float acc = 0.f;
    #pragma unroll
    for (int e = 0; e < EMB; ++e) acc = fmaf(ar[e], wp[e * 128], acc);
    Ws[i] = acc;
  } else {
    const int j = i - total_s;
    if (j < total_v) {
      const int bid = j >> 12;
      const int p = j & 4095;
      const int l = bid / NTYPES, t = bid % NTYPES;
      const int v = p >> 6, u = p & 63;
      const float* ar = embed + t * EMB;
      const float* wp = Wsv + ((size_t)(l * 64 + v) * EMB) * 64 + u;
      float acc = 0.f;
      #pragma unroll
      for (int e = 0; e < EMB; ++e) acc = fmaf(ar[e], wp[e * 64], acc);
      Wv[j] = acc;
    }
  }
}

// Wt[l][ch][j] = Wr2[l][j][ch] — transposed so a channel's 16 coeffs are
// contiguous (4x dwordx4 per lane).
__global__ void transpose_wr2(const float* __restrict__ Wr2, float* __restrict__ Wt)
{
  const int t = blockIdx.x * 256 + threadIdx.x;
  if (t >= LAYERS * 256) return;
  const int l = t >> 8, ch = t & 255;
  #pragma unroll
  for (int j = 0; j < RH; ++j)
    Wt[(size_t)l * 4096 + ch * RH + j] = Wr2[(size_t)l * 4096 + j * 256 + ch];
}

// ---------------------------------------------------------------------------
// Per-edge geometry + first MLP layer, in CSR order.
// ea4[k] = (eaX, eaY, eaZ, 0);  hidb[k][16] = f32 hidden activations.
// ---------------------------------------------------------------------------
__global__ void edge_geom(const float* __restrict__ xv,
                          const int* __restrict__ esrc_s, const int* __restrict__ edst_s,
                          const float* __restrict__ Wr1l, const float* __restrict__ br1l,
                          float4* __restrict__ ea4, float* __restrict__ hidb, int m)
{
  const int k = blockIdx.x * 256 + threadIdx.x;
  if (k >= m) return;
  const int s = esrc_s[k], d = edst_s[k];
  const float ex = xv[(size_t)s * 6 + 0] - xv[(size_t)d * 6 + 0];
  const float ey = xv[(size_t)s * 6 + 1] - xv[(size_t)d * 6 + 1];
  const float ez = xv[(size_t)s * 6 + 2] - xv[(size_t)d * 6 + 2];
  const float len = sqrtf(ex * ex + ey * ey + ez * ez);
  const float invl = 1.f / len;
  const float u = len * (1.f / CUTV);
  const float arg = (float)M_PI * u;
  float sa, ca;
  __sincosf(arg, &sa, &ca);
  const float vv = 2.f * (u - 1.f);
  float cut = 0.5f * (1.f - (2.f * ca * ca - 1.f));
  cut = (vv > 0.f) ? 0.f : cut;
  cut = (vv < -1.f) ? 1.f : cut;
  const float cc = cut * 1.7320508075688772f * invl;
  ea4[k] = make_float4(cc * ex, cc * ey, cc * ez, 0.f);
  float bess[NB];
  const float amp = 2.1380899352993948f * invl;  // sqrt(2/CUT)*sqrt(NB)
  const float twoc = 2.f * ca;
  float sm1 = 0.f, scur = sa;
  #pragma unroll
  for (int kk = 0; kk < NB; ++kk) {
    bess[kk] = amp * scur;
    const float snext = twoc * scur - sm1;
    sm1 = scur; scur = snext;
  }
  float hid[RH];
  #pragma unroll
  for (int j = 0; j < RH; ++j) {
    float h = br1l[j];
    #pragma unroll
    for (int kk = 0; kk < NB; ++kk) h = fmaf(bess[kk], Wr1l[kk * RH + j], h);
    hid[j] = h / (1.f + expf(-h));   // silu
  }
  float4* hp = (float4*)(hidb + (size_t)k * 16);
  hp[0] = make_float4(hid[0],  hid[1],  hid[2],  hid[3]);
  hp[1] = make_float4(hid[4],  hid[5],  hid[6],  hid[7]);
  hp[2] = make_float4(hid[8],  hid[9],  hid[10], hid[11]);
  hp[3] = make_float4(hid[12], hid[13], hid[14], hid[15]);
}

// ---------------------------------------------------------------------------
// One NODE per 256-thread block; wave q owns output-channel quarter q
// (A=wA, B=wB, C=wC, D=wD). Each lane holds only 16 Wr2 coefficients, so the
// allocator keeps them resident. hid/ea/esrc addresses are wave-uniform ->
// scalar loads (SGPRs). Only vector load per edge: the st gather (1-deep
// prefetch, src 2 ahead). Quarter partials + split node-phase partials are
// combined through LDS with a single barrier; wave 0 finishes.
// ---------------------------------------------------------------------------
#define EDGE_PIPELINE(QSTMT)                                                  \
  {                                                                           \
    int srcN = esrc_s[k0];                                                    \
    float4 stN = st_in[(size_t)srcN * 64 + lane];                             \
    const float4* hp0 = (const float4*)(hidb + (size_t)k0 * 16);              \
    float4 h0N = hp0[0], h1N = hp0[1], h2N = hp0[2], h3N = hp0[3];            \
    float4 eaN = ea4[k0];                                                     \
    srcN = (k0 + 1 < k1) ? esrc_s[k0 + 1] : srcN;                             \
    for (int k = k0; k < k1; ++k) {                                           \
      const float4 stc = stN, ea = eaN;                                       \
      const float4 g1 = h0N, g2 = h1N, g3 = h2N, g4 = h3N;                    \
      stN = st_in[(size_t)srcN * 64 + lane];                                  \
      const int kn = (k + 1 < k1) ? (k + 1) : k;                              \
      const float4* hp = (const float4*)(hidb + (size_t)kn * 16);             \
      h0N = hp[0]; h1N = hp[1]; h2N = hp[2]; h3N = hp[3];                     \
      eaN = ea4[kn];                                                          \
      srcN = (k + 2 < k1) ? esrc_s[k + 2] : srcN;                             \
      float w = bias;                                                         \
      w = fmaf(g1.x, W0.x, w); w = fmaf(g1.y, W0.y, w);                       \
      w = fmaf(g1.z, W0.z, w); w = fmaf(g1.w, W0.w, w);                       \
      w = fmaf(g2.x, W1.x, w); w = fmaf(g2.y, W1.y, w);                       \
      w = fmaf(g2.z, W1.z, w); w = fmaf(g2.w, W1.w, w);                       \
      w = fmaf(g3.x, W2.x, w); w = fmaf(g3.y, W2.y, w);                       \
      w = fmaf(g3.z, W2.z, w); w = fmaf(g3.w, W2.w, w);                       \
      w = fmaf(g4.x, W3.x, w); w = fmaf(g4.y, W3.y, w);                       \
      w = fmaf(g4.z, W3.z, w); w = fmaf(g4.w, W3.w, w);                       \
      QSTMT                                                                   \
    }                                                                         \
  }

__global__ __launch_bounds__(256, 4) void gather_update(
    const int* __restrict__ off, const int* __restrict__ esrc_s,
    const float4* __restrict__ ea4, const float* __restrict__ hidb,
    const float4* __restrict__ st_in, const int* __restrict__ nattr,
    const float* __restrict__ Ws, const float* __restrict__ Wv,
    const float* __restrict__ Wtl, const float* __restrict__ br2l,
    const float* __restrict__ Qm,
    float4* __restrict__ st_out, float* __restrict__ xv_out, int n)
{
  __shared__ float eAx[64], eAy[64], eAz[64], eCx[64], eCy[64], eCz[64];
  __shared__ float eB[64], eD[64];
  __shared__ float oP[4][5][64];
  const int lane = threadIdx.x & 63;
  const int wid = threadIdx.x >> 6;
  const int node = blockIdx.x;

  // 16 Wr2 coefficients for this (quarter, channel) — resident in VGPRs.
  const int chg = (wid << 6) + lane;
  const float* wp = Wtl + (size_t)chg * RH;
  const float4 W0 = *(const float4*)wp;
  const float4 W1 = *(const float4*)(wp + 4);
  const float4 W2 = *(const float4*)(wp + 8);
  const float4 W3 = *(const float4*)(wp + 12);
  const float bias = br2l[chg];

  float a0 = 0.f, a1 = 0.f, a2 = 0.f;
  const int k0 = off[node], k1 = off[node + 1];
  if (k0 < k1) {
    if (wid == 0) {
      EDGE_PIPELINE({
        const float t = w * stc.x;
        a0 = fmaf(t, ea.x, a0); a1 = fmaf(t, ea.y, a1); a2 = fmaf(t, ea.z, a2);
      })
    } else if (wid == 1) {
      EDGE_PIPELINE({
        const float dt = stc.y * ea.x + stc.z * ea.y + stc.w * ea.z;
        a0 = fmaf(w, dt, a0);
      })
    } else if (wid == 2) {
      EDGE_PIPELINE({
        a0 = fmaf(w, stc.z * ea.z - stc.w * ea.y, a0);
        a1 = fmaf(w, stc.w * ea.x - stc.y * ea.z, a1);
        a2 = fmaf(w, stc.y * ea.y - stc.z * ea.x, a2);
      })
    } else {
      EDGE_PIPELINE({
        const float dt = stc.y * ea.x + stc.z * ea.y + stc.w * ea.z;
        a0 = fmaf(w, dt, a0);
      })
    }
  }
  if (wid == 0)      { eAx[lane] = a0; eAy[lane] = a1; eAz[lane] = a2; }
  else if (wid == 1) { eB[lane] = a0; }
  else if (wid == 2) { eCx[lane] = a0; eCy[lane] = a1; eCz[lane] = a2; }
  else               { eD[lane] = a0; }

  // node phase: each wave does 16 of the 64 s2 values
  const int ty = nattr[node];
  const float* WsT = Ws + (size_t)ty * 8192;
  const float* WvT = Wv + (size_t)ty * 4096;
  const float4 own = st_in[(size_t)node * 64 + lane];
  float oS1 = 0.f, oS2 = 0.f, oV0 = 0.f, oV1 = 0.f, oV2 = 0.f;
  const int s20 = wid << 4;
  #pragma unroll 4
  for (int s2 = s20; s2 < s20 + 16; ++s2) {
    const float yss = __shfl(own.x, s2, 64);
    const float b0 = __shfl(own.y, s2, 64);
    const float b1 = __shfl(own.z, s2, 64);
    const float b2 = __shfl(own.w, s2, 64);
    oS1 = fmaf(yss, WsT[s2 * 128 + lane], oS1);
    oS2 = fmaf(yss, WsT[s2 * 128 + 64 + lane], oS2);
    const float wvv = WvT[s2 * 64 + lane];
    oV0 = fmaf(b0, wvv, oV0);
    oV1 = fmaf(b1, wvv, oV1);
    oV2 = fmaf(b2, wvv, oV2);
  }
  oP[wid][0][lane] = oS1; oP[wid][1][lane] = oS2;
  oP[wid][2][lane] = oV0; oP[wid][3][lane] = oV1; oP[wid][4][lane] = oV2;
  __syncthreads();

  if (wid == 0) {
    const float inv_deg = 0.17677669529663687f;  // 1/sqrt(32)
    const float aS1 = eB[lane], aS2 = eD[lane];
    const float aV0 = eAx[lane] + eCx[lane];
    const float aV1 = eAy[lane] + eCy[lane];
    const float aV2 = eAz[lane] + eCz[lane];
    float s1 = 0.f, s2v = 0.f, v0 = 0.f, v1 = 0.f, v2 = 0.f;
    #pragma unroll
    for (int q = 0; q < 4; ++q) {
      s1 += oP[q][0][lane]; s2v += oP[q][1][lane];
      v0 += oP[q][2][lane]; v1 += oP[q][3][lane]; v2 += oP[q][4][lane];
    }
    const float outS1 = s1 + aS1 * inv_deg;
    const float outS2 = s2v + aS2 * inv_deg;
    const float sig1 = 1.f / (1.f + expf(-outS1));
    const float gate = 1.f / (1.f + expf(-outS2));
    const float ysn = own.x + HSTEP * outS1 * sig1;
    const float gf = HSTEP * gate;
    const float yvn0 = own.y + gf * (v0 + aV0 * inv_deg);
    const float yvn1 = own.z + gf * (v1 + aV1 * inv_deg);
    const float yvn2 = own.w + gf * (v2 + aV2 * inv_deg);
    st_out[(size_t)node * 64 + lane] = make_float4(ysn, yvn0, yvn1, yvn2);

    // x_v projection: butterfly reduce 6 scalars over the wave
    const float q0 = Qm[lane * 2 + 0], q1 = Qm[lane * 2 + 1];
    float pr[6] = { yvn0 * q0, yvn1 * q0, yvn2 * q0,
                    yvn0 * q1, yvn1 * q1, yvn2 * q1 };
    #pragma unroll
    for (int mm = 1; mm < 64; mm <<= 1) {
      #pragma unroll
      for (int i = 0; i < 6; ++i) pr[i] += __shfl_xor(pr[i], mm, 64);
    }
    if (lane == 0) {
      #pragma unroll
      for (int i = 0; i < 6; ++i) xv_out[(size_t)node * 6 + i] = pr[i];
    }
  }
}

// ---------------------------------------------------------------------------
extern "C" void kernel_launch(void* const* d_in, const int* in_sizes, int n_in,
                              void* d_out, int out_size, void* d_ws, size_t ws_size,
                              hipStream_t stream)
{
  const float* x     = (const float*)d_in[0];
  const int*   nattr = (const int*)d_in[2];
  const int*   esrc  = (const int*)d_in[3];
  const int*   edst  = (const int*)d_in[4];
  const float* embed = (const float*)d_in[5];
  const float* Ku    = (const float*)d_in[6];
  const float* Wss   = (const float*)d_in[7];
  const float* Wsv   = (const float*)d_in[8];
  const float* Wr1   = (const float*)d_in[9];
  const float* br1   = (const float*)d_in[10];
  const float* Wr2   = (const float*)d_in[11];
  const float* br2   = (const float*)d_in[12];
  const int n = in_sizes[0] / 6;
  const int m = in_sizes[3];

  char* p = (char*)d_ws;
  auto alloc = [&](size_t bytes) -> char* {
    char* r = p;
    p += (bytes + 255) & ~(size_t)255;
    return r;
  };
  int*    off    = (int*)alloc((size_t)(n + 1) * 4);
  int*    cursor = (int*)alloc((size_t)n * 4);
  int*    csr    = (int*)alloc((size_t)m * 4);
  int*    esrc_s = (int*)alloc((size_t)m * 4);
  int*    edst_s = (int*)alloc((size_t)m * 4);
  float*  Q      = (float*)alloc(128 * 4);
  float*  Ws     = (float*)alloc((size_t)LAYERS * NTYPES * 64 * 128 * 4);
  float*  Wv     = (float*)alloc((size_t)LAYERS * NTYPES * 64 * 64 * 4);
  float4* st0    = (float4*)alloc((size_t)n * 64 * 16);
  float4* st1    = (float4*)alloc((size_t)n * 64 * 16);
  float*  xvb    = (float*)alloc((size_t)n * 6 * 4);
  float4* ea4    = (float4*)alloc((size_t)m * 16);
  float*  hidb   = (float*)alloc((size_t)m * 16 * 4);
  float*  Wt     = (float*)alloc((size_t)LAYERS * 4096 * 4);

  const int total_s = LAYERS * NTYPES * 64 * 128;
  const int total_v = LAYERS * NTYPES * 64 * 64;

  qr_kernel<<<1, 64, 0, stream>>>(Ku, Q);
  init_state<<<(n * 64 + 255) / 256, 256, 0, stream>>>(x, Q, st0, cursor, n);
  hist_kernel<<<(m + 255) / 256, 256, 0, stream>>>(edst, cursor, m);
  scan_kernel<<<1, 1024, 0, stream>>>(cursor, off, n);
  scatter_kernel<<<(m + 255) / 256, 256, 0, stream>>>(edst, cursor, csr, m);
  reorder_kernel<<<(m + 255) / 256, 256, 0, stream>>>(csr, esrc, edst, esrc_s, edst_s, m);
  type_weights<<<(total_s + total_v + 255) / 256, 256, 0, stream>>>(
      embed, Wss, Wsv, Ws, Wv, total_s, total_v);
  transpose_wr2<<<2, 256, 0, stream>>>(Wr2, Wt);

  const float* xv_cur = x;
  const float4* st_cur = st0;
  float4* st_nxt = st1;
  for (int l = 0; l < LAYERS; ++l) {
    edge_geom<<<(m + 255) / 256, 256, 0, stream>>>(
        xv_cur, esrc_s, edst_s, Wr1 + l * NB * RH, br1 + l * RH, ea4, hidb, m);
    float* xv_out = (l == LAYERS - 1) ? (float*)d_out : xvb;
    gather_update<<<n, 256, 0, stream>>>(
        off, esrc_s, ea4, hidb, st_cur, nattr,
        Ws + (size_t)l * NTYPES * 8192, Wv + (size_t)l * NTYPES * 4096,
        Wt + (size_t)l * 4096, br2 + l * 256, Q,
        st_nxt, xv_out, n);
    xv_cur = xv_out;
    float4* ts = (float4*)st_cur; st_cur = st_nxt; st_nxt = ts;
  }
}

// Round 12
// 305.386 us; speedup vs baseline: 1.1253x; 1.1253x over previous
//
#include <hip/hip_runtime.h>
#include <math.h>

#define NSC 64
#define NVC 64
#define EMB 32
#define NTYPES 20
#define NB 8
#define RH 16
#define LAYERS 2
#define CUTV 3.5f
#define HSTEP 0.1f

// ---------------------------------------------------------------------------
// Exact LAPACK-style Householder QR of Ku^T (64x2) -> Q (64x2), wave-parallel.
// ---------------------------------------------------------------------------
__device__ __forceinline__ float wave_sum(float t)
{
  #pragma unroll
  for (int mm = 1; mm < 64; mm <<= 1) t += __shfl_xor(t, mm, 64);
  return t;
}

__global__ void qr_kernel(const float* __restrict__ Ku, float* __restrict__ Q)
{
  const int i = threadIdx.x;  // 64 lanes
  float a0 = Ku[i], a1 = Ku[64 + i];
  const float xn2 = wave_sum((i >= 1) ? a0 * a0 : 0.f);
  const float alpha = __shfl(a0, 0, 64);
  const float beta0 = -copysignf(sqrtf(alpha * alpha + xn2), alpha);
  const float tau0 = (beta0 - alpha) / beta0;
  const float inv0 = 1.f / (alpha - beta0);
  const float v0 = (i == 0) ? 1.f : a0 * inv0;
  const float w = wave_sum(v0 * a1);
  a1 -= tau0 * w * v0;
  const float alpha1 = __shfl(a1, 1, 64);
  const float xn2b = wave_sum((i >= 2) ? a1 * a1 : 0.f);
  const float beta1 = -copysignf(sqrtf(alpha1 * alpha1 + xn2b), alpha1);
  const float tau1 = (beta1 - alpha1) / beta1;
  const float inv1 = 1.f / (alpha1 - beta1);
  const float v1 = (i == 0) ? 0.f : ((i == 1) ? 1.f : a1 * inv1);
  const float t1v = ((i == 1) ? 1.f : 0.f) - tau1 * v1;
  const float d = wave_sum(v0 * t1v);
  Q[i * 2 + 0] = ((i == 0) ? 1.f : 0.f) - tau0 * v0;
  Q[i * 2 + 1] = t1v - tau0 * d * v0;
}

// ---------------------------------------------------------------------------
// State layout: st4[node*64+lane] = (s, vx, vy, vz) — one float4 per (node,ch).
// ---------------------------------------------------------------------------
__global__ void init_state(const float* __restrict__ x, const float* __restrict__ Qm,
                           float4* __restrict__ st0, int* __restrict__ cnt, int n)
{
  const int i = blockIdx.x * 256 + threadIdx.x;
  const int node = i >> 6, lane = i & 63;
  if (node < n) {
    const float q0 = Qm[lane * 2 + 0], q1 = Qm[lane * 2 + 1];
    const float* xp = x + (size_t)node * 6;
    st0[i] = make_float4(0.f,
                         xp[0] * q0 + xp[3] * q1,
                         xp[1] * q0 + xp[4] * q1,
                         xp[2] * q0 + xp[5] * q1);
  }
  if (i < n) cnt[i] = 0;
}

__global__ void hist_kernel(const int* __restrict__ edst, int* __restrict__ cnt, int m)
{
  const int e = blockIdx.x * 256 + threadIdx.x;
  if (e < m) atomicAdd(&cnt[edst[e]], 1);
}

// Single-block exclusive scan of counts.
__global__ void scan_kernel(int* cnt, int* off, int n)
{
  __shared__ int lds[1024];
  const int t = threadIdx.x;
  const int CH = (n + 1023) >> 10;
  const int base = t * CH;
  int local[16];
  int run = 0;
  for (int j = 0; j < CH; ++j) {
    int v = (base + j < n) ? cnt[base + j] : 0;
    local[j] = run;
    run += v;
  }
  lds[t] = run;
  __syncthreads();
  for (int s = 1; s < 1024; s <<= 1) {
    int v = (t >= s) ? lds[t - s] : 0;
    __syncthreads();
    lds[t] += v;
    __syncthreads();
  }
  const int excl = lds[t] - run;
  for (int j = 0; j < CH; ++j) {
    if (base + j < n) {
      int o = excl + local[j];
      off[base + j] = o;
      cnt[base + j] = o;
    }
  }
  if (t == 1023) off[n] = lds[1023];
}

// Scatter edges into CSR order, writing the reordered src/dst arrays directly.
__global__ void scatter_kernel(const int* __restrict__ esrc, const int* __restrict__ edst,
                               int* __restrict__ cursor,
                               int* __restrict__ esrc_s, int* __restrict__ edst_s, int m)
{
  const int e = blockIdx.x * 256 + threadIdx.x;
  if (e < m) {
    const int d = edst[e];
    int p = atomicAdd(&cursor[d], 1);
    esrc_s[p] = esrc[e];
    edst_s[p] = d;
  }
}

// ---------------------------------------------------------------------------
// Per-(layer,type) folded self-connection weights, output-parallel.
// ---------------------------------------------------------------------------
__global__ void type_weights(const float* __restrict__ embed,
                             const float* __restrict__ Wss,
                             const float* __restrict__ Wsv,
                             float* __restrict__ Ws, float* __restrict__ Wv,
                             int total_s, int total_v)
{
  const int i = blockIdx.x * 256 + threadIdx.x;
  if (i < total_s) {
    const int bid = i >> 13;
    const int p = i & 8191;
    const int l = bid / NTYPES, t = bid % NTYPES;
    const int s = p >> 7, o = p & 127;
    const float* ar = embed + t * EMB;
    const float* wp = Wss + ((size_t)(l * 64 + s) * EMB) * 128 + o;
    float acc = 0.f;
    #pragma unroll
    for (int e = 0; e < EMB; ++e) acc = fmaf(ar[e], wp[e * 128], acc);
    Ws[i] = acc;
  } else {
    const int j = i - total_s;
    if (j < total_v) {
      const int bid = j >> 12;
      const int p = j & 4095;
      const int l = bid / NTYPES, t = bid % NTYPES;
      const int v = p >> 6, u = p & 63;
      const float* ar = embed + t * EMB;
      const float* wp = Wsv + ((size_t)(l * 64 + v) * EMB) * 64 + u;
      float acc = 0.f;
      #pragma unroll
      for (int e = 0; e < EMB; ++e) acc = fmaf(ar[e], wp[e * 64], acc);
      Wv[j] = acc;
    }
  }
}

// Wt[l][ch][j] = Wr2[l][j][ch] — transposed so a channel's 16 coeffs are
// contiguous (4x dwordx4 per lane).
__global__ void transpose_wr2(const float* __restrict__ Wr2, float* __restrict__ Wt)
{
  const int t = blockIdx.x * 256 + threadIdx.x;
  if (t >= LAYERS * 256) return;
  const int l = t >> 8, ch = t & 255;
  #pragma unroll
  for (int j = 0; j < RH; ++j)
    Wt[(size_t)l * 4096 + ch * RH + j] = Wr2[(size_t)l * 4096 + j * 256 + ch];
}

// ---------------------------------------------------------------------------
// Per-edge geometry + first MLP layer, in CSR order.
// ea4[k] = (eaX, eaY, eaZ, 0);  hidb[k][16] = f32 hidden activations.
// ---------------------------------------------------------------------------
__global__ void edge_geom(const float* __restrict__ xv,
                          const int* __restrict__ esrc_s, const int* __restrict__ edst_s,
                          const float* __restrict__ Wr1l, const float* __restrict__ br1l,
                          float4* __restrict__ ea4, float* __restrict__ hidb, int m)
{
  const int k = blockIdx.x * 256 + threadIdx.x;
  if (k >= m) return;
  const int s = esrc_s[k], d = edst_s[k];
  const float ex = xv[(size_t)s * 6 + 0] - xv[(size_t)d * 6 + 0];
  const float ey = xv[(size_t)s * 6 + 1] - xv[(size_t)d * 6 + 1];
  const float ez = xv[(size_t)s * 6 + 2] - xv[(size_t)d * 6 + 2];
  const float len = sqrtf(ex * ex + ey * ey + ez * ez);
  const float invl = 1.f / len;
  const float u = len * (1.f / CUTV);
  const float arg = (float)M_PI * u;
  float sa, ca;
  __sincosf(arg, &sa, &ca);
  const float vv = 2.f * (u - 1.f);
  float cut = 0.5f * (1.f - (2.f * ca * ca - 1.f));
  cut = (vv > 0.f) ? 0.f : cut;
  cut = (vv < -1.f) ? 1.f : cut;
  const float cc = cut * 1.7320508075688772f * invl;
  ea4[k] = make_float4(cc * ex, cc * ey, cc * ez, 0.f);
  float bess[NB];
  const float amp = 2.1380899352993948f * invl;  // sqrt(2/CUT)*sqrt(NB)
  const float twoc = 2.f * ca;
  float sm1 = 0.f, scur = sa;
  #pragma unroll
  for (int kk = 0; kk < NB; ++kk) {
    bess[kk] = amp * scur;
    const float snext = twoc * scur - sm1;
    sm1 = scur; scur = snext;
  }
  float hid[RH];
  #pragma unroll
  for (int j = 0; j < RH; ++j) {
    float h = br1l[j];
    #pragma unroll
    for (int kk = 0; kk < NB; ++kk) h = fmaf(bess[kk], Wr1l[kk * RH + j], h);
    hid[j] = h / (1.f + expf(-h));   // silu
  }
  float4* hp = (float4*)(hidb + (size_t)k * 16);
  hp[0] = make_float4(hid[0],  hid[1],  hid[2],  hid[3]);
  hp[1] = make_float4(hid[4],  hid[5],  hid[6],  hid[7]);
  hp[2] = make_float4(hid[8],  hid[9],  hid[10], hid[11]);
  hp[3] = make_float4(hid[12], hid[13], hid[14], hid[15]);
}

// ---------------------------------------------------------------------------
// One NODE per 256-thread block; wave q owns output-channel quarter q.
// Each lane holds 16 Wr2 coefficients (resident). Edges processed in batches
// of 4: all 4 random st gathers issued back-to-back (4-way MLP) before any
// consumption, amortizing the L2/L3 miss latency over 4 edges. hid loads
// stay per-edge (sequential stream -> cache-hit).
// ---------------------------------------------------------------------------
#define MLPW                                                                  \
  float w = bias;                                                             \
  w = fmaf(g1.x, W0.x, w); w = fmaf(g1.y, W0.y, w);                           \
  w = fmaf(g1.z, W0.z, w); w = fmaf(g1.w, W0.w, w);                           \
  w = fmaf(g2.x, W1.x, w); w = fmaf(g2.y, W1.y, w);                           \
  w = fmaf(g2.z, W1.z, w); w = fmaf(g2.w, W1.w, w);                           \
  w = fmaf(g3.x, W2.x, w); w = fmaf(g3.y, W2.y, w);                           \
  w = fmaf(g3.z, W2.z, w); w = fmaf(g3.w, W2.w, w);                           \
  w = fmaf(g4.x, W3.x, w); w = fmaf(g4.y, W3.y, w);                           \
  w = fmaf(g4.z, W3.z, w); w = fmaf(g4.w, W3.w, w);

#define EDGE_PIPELINE(QSTMT)                                                  \
  {                                                                           \
    int k = k0;                                                               \
    for (; k + 4 <= k1; k += 4) {                                             \
      const int sA = esrc_s[k],     sB = esrc_s[k + 1];                       \
      const int sC = esrc_s[k + 2], sD = esrc_s[k + 3];                       \
      const float4 stA = st_in[(size_t)sA * 64 + lane];                       \
      const float4 stB = st_in[(size_t)sB * 64 + lane];                       \
      const float4 stC = st_in[(size_t)sC * 64 + lane];                       \
      const float4 stD = st_in[(size_t)sD * 64 + lane];                       \
      const float4 eaA = ea4[k],     eaB = ea4[k + 1];                        \
      const float4 eaC = ea4[k + 2], eaD = ea4[k + 3];                        \
      const float4* hb = (const float4*)(hidb + (size_t)k * 16);              \
      { const float4 g1 = hb[0], g2 = hb[1], g3 = hb[2], g4 = hb[3];          \
        const float4 stc = stA, ea = eaA; MLPW; QSTMT }                       \
      { const float4 g1 = hb[4], g2 = hb[5], g3 = hb[6], g4 = hb[7];          \
        const float4 stc = stB, ea = eaB; MLPW; QSTMT }                       \
      { const float4 g1 = hb[8], g2 = hb[9], g3 = hb[10], g4 = hb[11];        \
        const float4 stc = stC, ea = eaC; MLPW; QSTMT }                       \
      { const float4 g1 = hb[12], g2 = hb[13], g3 = hb[14], g4 = hb[15];      \
        const float4 stc = stD, ea = eaD; MLPW; QSTMT }                       \
    }                                                                         \
    for (; k < k1; ++k) {                                                     \
      const int sA = esrc_s[k];                                               \
      const float4 stc = st_in[(size_t)sA * 64 + lane];                       \
      const float4* hb = (const float4*)(hidb + (size_t)k * 16);              \
      const float4 g1 = hb[0], g2 = hb[1], g3 = hb[2], g4 = hb[3];            \
      const float4 ea = ea4[k];                                               \
      MLPW; QSTMT                                                             \
    }                                                                         \
  }

__global__ __launch_bounds__(256, 3) void gather_update(
    const int* __restrict__ off, const int* __restrict__ esrc_s,
    const float4* __restrict__ ea4, const float* __restrict__ hidb,
    const float4* __restrict__ st_in, const int* __restrict__ nattr,
    const float* __restrict__ Ws, const float* __restrict__ Wv,
    const float* __restrict__ Wtl, const float* __restrict__ br2l,
    const float* __restrict__ Qm,
    float4* __restrict__ st_out, float* __restrict__ xv_out, int n)
{
  __shared__ float eAx[64], eAy[64], eAz[64], eCx[64], eCy[64], eCz[64];
  __shared__ float eB[64], eD[64];
  __shared__ float oP[4][5][64];
  const int lane = threadIdx.x & 63;
  const int wid = threadIdx.x >> 6;
  const int node = blockIdx.x;

  // 16 Wr2 coefficients for this (quarter, channel) — resident in VGPRs.
  const int chg = (wid << 6) + lane;
  const float* wp = Wtl + (size_t)chg * RH;
  const float4 W0 = *(const float4*)wp;
  const float4 W1 = *(const float4*)(wp + 4);
  const float4 W2 = *(const float4*)(wp + 8);
  const float4 W3 = *(const float4*)(wp + 12);
  const float bias = br2l[chg];

  float a0 = 0.f, a1 = 0.f, a2 = 0.f;
  const int k0 = off[node], k1 = off[node + 1];
  if (k0 < k1) {
    if (wid == 0) {
      EDGE_PIPELINE({
        const float t = w * stc.x;
        a0 = fmaf(t, ea.x, a0); a1 = fmaf(t, ea.y, a1); a2 = fmaf(t, ea.z, a2);
      })
    } else if (wid == 1) {
      EDGE_PIPELINE({
        const float dt = stc.y * ea.x + stc.z * ea.y + stc.w * ea.z;
        a0 = fmaf(w, dt, a0);
      })
    } else if (wid == 2) {
      EDGE_PIPELINE({
        a0 = fmaf(w, stc.z * ea.z - stc.w * ea.y, a0);
        a1 = fmaf(w, stc.w * ea.x - stc.y * ea.z, a1);
        a2 = fmaf(w, stc.y * ea.y - stc.z * ea.x, a2);
      })
    } else {
      EDGE_PIPELINE({
        const float dt = stc.y * ea.x + stc.z * ea.y + stc.w * ea.z;
        a0 = fmaf(w, dt, a0);
      })
    }
  }
  if (wid == 0)      { eAx[lane] = a0; eAy[lane] = a1; eAz[lane] = a2; }
  else if (wid == 1) { eB[lane] = a0; }
  else if (wid == 2) { eCx[lane] = a0; eCy[lane] = a1; eCz[lane] = a2; }
  else               { eD[lane] = a0; }

  // node phase: each wave does 16 of the 64 s2 values
  const int ty = nattr[node];
  const float* WsT = Ws + (size_t)ty * 8192;
  const float* WvT = Wv + (size_t)ty * 4096;
  const float4 own = st_in[(size_t)node * 64 + lane];
  float oS1 = 0.f, oS2 = 0.f, oV0 = 0.f, oV1 = 0.f, oV2 = 0.f;
  const int s20 = wid << 4;
  #pragma unroll 4
  for (int s2 = s20; s2 < s20 + 16; ++s2) {
    const float yss = __shfl(own.x, s2, 64);
    const float b0 = __shfl(own.y, s2, 64);
    const float b1 = __shfl(own.z, s2, 64);
    const float b2 = __shfl(own.w, s2, 64);
    oS1 = fmaf(yss, WsT[s2 * 128 + lane], oS1);
    oS2 = fmaf(yss, WsT[s2 * 128 + 64 + lane], oS2);
    const float wvv = WvT[s2 * 64 + lane];
    oV0 = fmaf(b0, wvv, oV0);
    oV1 = fmaf(b1, wvv, oV1);
    oV2 = fmaf(b2, wvv, oV2);
  }
  oP[wid][0][lane] = oS1; oP[wid][1][lane] = oS2;
  oP[wid][2][lane] = oV0; oP[wid][3][lane] = oV1; oP[wid][4][lane] = oV2;
  __syncthreads();

  if (wid == 0) {
    const float inv_deg = 0.17677669529663687f;  // 1/sqrt(32)
    const float aS1 = eB[lane], aS2 = eD[lane];
    const float aV0 = eAx[lane] + eCx[lane];
    const float aV1 = eAy[lane] + eCy[lane];
    const float aV2 = eAz[lane] + eCz[lane];
    float s1 = 0.f, s2v = 0.f, v0 = 0.f, v1 = 0.f, v2 = 0.f;
    #pragma unroll
    for (int q = 0; q < 4; ++q) {
      s1 += oP[q][0][lane]; s2v += oP[q][1][lane];
      v0 += oP[q][2][lane]; v1 += oP[q][3][lane]; v2 += oP[q][4][lane];
    }
    const float outS1 = s1 + aS1 * inv_deg;
    const float outS2 = s2v + aS2 * inv_deg;
    const float sig1 = 1.f / (1.f + expf(-outS1));
    const float gate = 1.f / (1.f + expf(-outS2));
    const float ysn = own.x + HSTEP * outS1 * sig1;
    const float gf = HSTEP * gate;
    const float yvn0 = own.y + gf * (v0 + aV0 * inv_deg);
    const float yvn1 = own.z + gf * (v1 + aV1 * inv_deg);
    const float yvn2 = own.w + gf * (v2 + aV2 * inv_deg);
    st_out[(size_t)node * 64 + lane] = make_float4(ysn, yvn0, yvn1, yvn2);

    // x_v projection: butterfly reduce 6 scalars over the wave
    const float q0 = Qm[lane * 2 + 0], q1 = Qm[lane * 2 + 1];
    float pr[6] = { yvn0 * q0, yvn1 * q0, yvn2 * q0,
                    yvn0 * q1, yvn1 * q1, yvn2 * q1 };
    #pragma unroll
    for (int mm = 1; mm < 64; mm <<= 1) {
      #pragma unroll
      for (int i = 0; i < 6; ++i) pr[i] += __shfl_xor(pr[i], mm, 64);
    }
    if (lane == 0) {
      #pragma unroll
      for (int i = 0; i < 6; ++i) xv_out[(size_t)node * 6 + i] = pr[i];
    }
  }
}

// ---------------------------------------------------------------------------
extern "C" void kernel_launch(void* const* d_in, const int* in_sizes, int n_in,
                              void* d_out, int out_size, void* d_ws, size_t ws_size,
                              hipStream_t stream)
{
  const float* x     = (const float*)d_in[0];
  const int*   nattr = (const int*)d_in[2];
  const int*   esrc  = (const int*)d_in[3];
  const int*   edst  = (const int*)d_in[4];
  const float* embed = (const float*)d_in[5];
  const float* Ku    = (const float*)d_in[6];
  const float* Wss   = (const float*)d_in[7];
  const float* Wsv   = (const float*)d_in[8];
  const float* Wr1   = (const float*)d_in[9];
  const float* br1   = (const float*)d_in[10];
  const float* Wr2   = (const float*)d_in[11];
  const float* br2   = (const float*)d_in[12];
  const int n = in_sizes[0] / 6;
  const int m = in_sizes[3];

  char* p = (char*)d_ws;
  auto alloc = [&](size_t bytes) -> char* {
    char* r = p;
    p += (bytes + 255) & ~(size_t)255;
    return r;
  };
  int*    off    = (int*)alloc((size_t)(n + 1) * 4);
  int*    cursor = (int*)alloc((size_t)n * 4);
  int*    esrc_s = (int*)alloc((size_t)m * 4);
  int*    edst_s = (int*)alloc((size_t)m * 4);
  float*  Q      = (float*)alloc(128 * 4);
  float*  Ws     = (float*)alloc((size_t)LAYERS * NTYPES * 64 * 128 * 4);
  float*  Wv     = (float*)alloc((size_t)LAYERS * NTYPES * 64 * 64 * 4);
  float4* st0    = (float4*)alloc((size_t)n * 64 * 16);
  float4* st1    = (float4*)alloc((size_t)n * 64 * 16);
  float*  xvb    = (float*)alloc((size_t)n * 6 * 4);
  float4* ea4    = (float4*)alloc((size_t)m * 16);
  float*  hidb   = (float*)alloc((size_t)m * 16 * 4);
  float*  Wt     = (float*)alloc((size_t)LAYERS * 4096 * 4);

  const int total_s = LAYERS * NTYPES * 64 * 128;
  const int total_v = LAYERS * NTYPES * 64 * 64;

  qr_kernel<<<1, 64, 0, stream>>>(Ku, Q);
  init_state<<<(n * 64 + 255) / 256, 256, 0, stream>>>(x, Q, st0, cursor, n);
  hist_kernel<<<(m + 255) / 256, 256, 0, stream>>>(edst, cursor, m);
  scan_kernel<<<1, 1024, 0, stream>>>(cursor, off, n);
  scatter_kernel<<<(m + 255) / 256, 256, 0, stream>>>(esrc, edst, cursor, esrc_s, edst_s, m);
  type_weights<<<(total_s + total_v + 255) / 256, 256, 0, stream>>>(
      embed, Wss, Wsv, Ws, Wv, total_s, total_v);
  transpose_wr2<<<2, 256, 0, stream>>>(Wr2, Wt);

  const float* xv_cur = x;
  const float4* st_cur = st0;
  float4* st_nxt = st1;
  for (int l = 0; l < LAYERS; ++l) {
    edge_geom<<<(m + 255) / 256, 256, 0, stream>>>(
        xv_cur, esrc_s, edst_s, Wr1 + l * NB * RH, br1 + l * RH, ea4, hidb, m);
    float* xv_out = (l == LAYERS - 1) ? (float*)d_out : xvb;
    gather_update<<<n, 256, 0, stream>>>(
        off, esrc_s, ea4, hidb, st_cur, nattr,
        Ws + (size_t)l * NTYPES * 8192, Wv + (size_t)l * NTYPES * 4096,
        Wt + (size_t)l * 4096, br2 + l * 256, Q,
        st_nxt, xv_out, n);
    xv_cur = xv_out;
    float4* ts = (float4*)st_cur; st_cur = st_nxt; st_nxt = ts;
  }
}

// Round 13
// 295.218 us; speedup vs baseline: 1.1640x; 1.0344x over previous
//
#include <hip/hip_runtime.h>
#include <math.h>

#define NSC 64
#define NVC 64
#define EMB 32
#define NTYPES 20
#define NB 8
#define RH 16
#define LAYERS 2
#define CUTV 3.5f
#define HSTEP 0.1f

// ---------------------------------------------------------------------------
// Exact LAPACK-style Householder QR of Ku^T (64x2) -> Q (64x2), wave-parallel.
// ---------------------------------------------------------------------------
__device__ __forceinline__ float wave_sum(float t)
{
  #pragma unroll
  for (int mm = 1; mm < 64; mm <<= 1) t += __shfl_xor(t, mm, 64);
  return t;
}

__global__ void qr_kernel(const float* __restrict__ Ku, float* __restrict__ Q)
{
  const int i = threadIdx.x;  // 64 lanes
  float a0 = Ku[i], a1 = Ku[64 + i];
  const float xn2 = wave_sum((i >= 1) ? a0 * a0 : 0.f);
  const float alpha = __shfl(a0, 0, 64);
  const float beta0 = -copysignf(sqrtf(alpha * alpha + xn2), alpha);
  const float tau0 = (beta0 - alpha) / beta0;
  const float inv0 = 1.f / (alpha - beta0);
  const float v0 = (i == 0) ? 1.f : a0 * inv0;
  const float w = wave_sum(v0 * a1);
  a1 -= tau0 * w * v0;
  const float alpha1 = __shfl(a1, 1, 64);
  const float xn2b = wave_sum((i >= 2) ? a1 * a1 : 0.f);
  const float beta1 = -copysignf(sqrtf(alpha1 * alpha1 + xn2b), alpha1);
  const float tau1 = (beta1 - alpha1) / beta1;
  const float inv1 = 1.f / (alpha1 - beta1);
  const float v1 = (i == 0) ? 0.f : ((i == 1) ? 1.f : a1 * inv1);
  const float t1v = ((i == 1) ? 1.f : 0.f) - tau1 * v1;
  const float d = wave_sum(v0 * t1v);
  Q[i * 2 + 0] = ((i == 0) ? 1.f : 0.f) - tau0 * v0;
  Q[i * 2 + 1] = t1v - tau0 * d * v0;
}

// ---------------------------------------------------------------------------
// State layout: st4[node*64+lane] = (s, vx, vy, vz) — one float4 per (node,ch).
// ---------------------------------------------------------------------------
__global__ void init_state(const float* __restrict__ x, const float* __restrict__ Qm,
                           float4* __restrict__ st0, int* __restrict__ cnt, int n)
{
  const int i = blockIdx.x * 256 + threadIdx.x;
  const int node = i >> 6, lane = i & 63;
  if (node < n) {
    const float q0 = Qm[lane * 2 + 0], q1 = Qm[lane * 2 + 1];
    const float* xp = x + (size_t)node * 6;
    st0[i] = make_float4(0.f,
                         xp[0] * q0 + xp[3] * q1,
                         xp[1] * q0 + xp[4] * q1,
                         xp[2] * q0 + xp[5] * q1);
  }
  if (i < n) cnt[i] = 0;
}

__global__ void hist_kernel(const int* __restrict__ edst, int* __restrict__ cnt, int m)
{
  const int e = blockIdx.x * 256 + threadIdx.x;
  if (e < m) atomicAdd(&cnt[edst[e]], 1);
}

// Single-block exclusive scan of counts.
__global__ void scan_kernel(int* cnt, int* off, int n)
{
  __shared__ int lds[1024];
  const int t = threadIdx.x;
  const int CH = (n + 1023) >> 10;
  const int base = t * CH;
  int local[16];
  int run = 0;
  for (int j = 0; j < CH; ++j) {
    int v = (base + j < n) ? cnt[base + j] : 0;
    local[j] = run;
    run += v;
  }
  lds[t] = run;
  __syncthreads();
  for (int s = 1; s < 1024; s <<= 1) {
    int v = (t >= s) ? lds[t - s] : 0;
    __syncthreads();
    lds[t] += v;
    __syncthreads();
  }
  const int excl = lds[t] - run;
  for (int j = 0; j < CH; ++j) {
    if (base + j < n) {
      int o = excl + local[j];
      off[base + j] = o;
      cnt[base + j] = o;
    }
  }
  if (t == 1023) off[n] = lds[1023];
}

// Scatter edges into CSR order, writing the reordered src/dst arrays directly.
__global__ void scatter_kernel(const int* __restrict__ esrc, const int* __restrict__ edst,
                               int* __restrict__ cursor,
                               int* __restrict__ esrc_s, int* __restrict__ edst_s, int m)
{
  const int e = blockIdx.x * 256 + threadIdx.x;
  if (e < m) {
    const int d = edst[e];
    int p = atomicAdd(&cursor[d], 1);
    esrc_s[p] = esrc[e];
    edst_s[p] = d;
  }
}

// ---------------------------------------------------------------------------
// Per-(layer,type) folded self-connection weights, output-parallel.
// ---------------------------------------------------------------------------
__global__ void type_weights(const float* __restrict__ embed,
                             const float* __restrict__ Wss,
                             const float* __restrict__ Wsv,
                             float* __restrict__ Ws, float* __restrict__ Wv,
                             int total_s, int total_v)
{
  const int i = blockIdx.x * 256 + threadIdx.x;
  if (i < total_s) {
    const int bid = i >> 13;
    const int p = i & 8191;
    const int l = bid / NTYPES, t = bid % NTYPES;
    const int s = p >> 7, o = p & 127;
    const float* ar = embed + t * EMB;
    const float* wp = Wss + ((size_t)(l * 64 + s) * EMB) * 128 + o;
    float acc = 0.f;
    #pragma unroll
    for (int e = 0; e < EMB; ++e) acc = fmaf(ar[e], wp[e * 128], acc);
    Ws[i] = acc;
  } else {
    const int j = i - total_s;
    if (j < total_v) {
      const int bid = j >> 12;
      const int p = j & 4095;
      const int l = bid / NTYPES, t = bid % NTYPES;
      const int v = p >> 6, u = p & 63;
      const float* ar = embed + t * EMB;
      const float* wp = Wsv + ((size_t)(l * 64 + v) * EMB) * 64 + u;
      float acc = 0.f;
      #pragma unroll
      for (int e = 0; e < EMB; ++e) acc = fmaf(ar[e], wp[e * 64], acc);
      Wv[j] = acc;
    }
  }
}

// Wt[l][ch][j] = Wr2[l][j][ch] — transposed so a channel's 16 coeffs are
// contiguous (4x dwordx4 per lane).
__global__ void transpose_wr2(const float* __restrict__ Wr2, float* __restrict__ Wt)
{
  const int t = blockIdx.x * 256 + threadIdx.x;
  if (t >= LAYERS * 256) return;
  const int l = t >> 8, ch = t & 255;
  #pragma unroll
  for (int j = 0; j < RH; ++j)
    Wt[(size_t)l * 4096 + ch * RH + j] = Wr2[(size_t)l * 4096 + j * 256 + ch];
}

// ---------------------------------------------------------------------------
// Per-edge geometry + first MLP layer, in CSR order.
// ea4[k] = (eaX, eaY, eaZ, 0);  hidb[k][16] = f32 hidden activations.
// ---------------------------------------------------------------------------
__global__ void edge_geom(const float* __restrict__ xv,
                          const int* __restrict__ esrc_s, const int* __restrict__ edst_s,
                          const float* __restrict__ Wr1l, const float* __restrict__ br1l,
                          float4* __restrict__ ea4, float* __restrict__ hidb, int m)
{
  const int k = blockIdx.x * 256 + threadIdx.x;
  if (k >= m) return;
  const int s = esrc_s[k], d = edst_s[k];
  const float ex = xv[(size_t)s * 6 + 0] - xv[(size_t)d * 6 + 0];
  const float ey = xv[(size_t)s * 6 + 1] - xv[(size_t)d * 6 + 1];
  const float ez = xv[(size_t)s * 6 + 2] - xv[(size_t)d * 6 + 2];
  const float len = sqrtf(ex * ex + ey * ey + ez * ez);
  const float invl = 1.f / len;
  const float u = len * (1.f / CUTV);
  const float arg = (float)M_PI * u;
  float sa, ca;
  __sincosf(arg, &sa, &ca);
  const float vv = 2.f * (u - 1.f);
  float cut = 0.5f * (1.f - (2.f * ca * ca - 1.f));
  cut = (vv > 0.f) ? 0.f : cut;
  cut = (vv < -1.f) ? 1.f : cut;
  const float cc = cut * 1.7320508075688772f * invl;
  ea4[k] = make_float4(cc * ex, cc * ey, cc * ez, 0.f);
  float bess[NB];
  const float amp = 2.1380899352993948f * invl;  // sqrt(2/CUT)*sqrt(NB)
  const float twoc = 2.f * ca;
  float sm1 = 0.f, scur = sa;
  #pragma unroll
  for (int kk = 0; kk < NB; ++kk) {
    bess[kk] = amp * scur;
    const float snext = twoc * scur - sm1;
    sm1 = scur; scur = snext;
  }
  float hid[RH];
  #pragma unroll
  for (int j = 0; j < RH; ++j) {
    float h = br1l[j];
    #pragma unroll
    for (int kk = 0; kk < NB; ++kk) h = fmaf(bess[kk], Wr1l[kk * RH + j], h);
    hid[j] = h / (1.f + expf(-h));   // silu
  }
  float4* hp = (float4*)(hidb + (size_t)k * 16);
  hp[0] = make_float4(hid[0],  hid[1],  hid[2],  hid[3]);
  hp[1] = make_float4(hid[4],  hid[5],  hid[6],  hid[7]);
  hp[2] = make_float4(hid[8],  hid[9],  hid[10], hid[11]);
  hp[3] = make_float4(hid[12], hid[13], hid[14], hid[15]);
}

// ---------------------------------------------------------------------------
// One NODE per 256-thread block; wave q owns output-channel quarter q.
// Each lane holds 16 Wr2 coefficients (resident in VGPRs). Edges processed
// in batches of 8: all 8 random st gathers issued back-to-back before any
// consumption, amortizing L2/L3 miss latency over 8 edges. esrc/ea/hid
// addresses are wave-uniform -> scalar (SGPR) loads.
// ---------------------------------------------------------------------------
#define MLPW                                                                  \
  float w = bias;                                                             \
  w = fmaf(g1.x, W0.x, w); w = fmaf(g1.y, W0.y, w);                           \
  w = fmaf(g1.z, W0.z, w); w = fmaf(g1.w, W0.w, w);                           \
  w = fmaf(g2.x, W1.x, w); w = fmaf(g2.y, W1.y, w);                           \
  w = fmaf(g2.z, W1.z, w); w = fmaf(g2.w, W1.w, w);                           \
  w = fmaf(g3.x, W2.x, w); w = fmaf(g3.y, W2.y, w);                           \
  w = fmaf(g3.z, W2.z, w); w = fmaf(g3.w, W2.w, w);                           \
  w = fmaf(g4.x, W3.x, w); w = fmaf(g4.y, W3.y, w);                           \
  w = fmaf(g4.z, W3.z, w); w = fmaf(g4.w, W3.w, w);

#define EDGE_PIPELINE(QSTMT)                                                  \
  {                                                                           \
    int k = k0;                                                               \
    for (; k + 8 <= k1; k += 8) {                                             \
      int srcP[8];                                                            \
      _Pragma("unroll")                                                       \
      for (int j = 0; j < 8; ++j) srcP[j] = esrc_s[k + j];                    \
      float4 stP[8];                                                          \
      _Pragma("unroll")                                                       \
      for (int j = 0; j < 8; ++j)                                             \
        stP[j] = st_in[(size_t)srcP[j] * 64 + lane];                          \
      float4 eaP[8];                                                          \
      _Pragma("unroll")                                                       \
      for (int j = 0; j < 8; ++j) eaP[j] = ea4[k + j];                        \
      const float4* hb = (const float4*)(hidb + (size_t)k * 16);              \
      _Pragma("unroll")                                                       \
      for (int j = 0; j < 8; ++j) {                                           \
        const float4 g1 = hb[4 * j + 0], g2 = hb[4 * j + 1];                  \
        const float4 g3 = hb[4 * j + 2], g4 = hb[4 * j + 3];                  \
        const float4 stc = stP[j], ea = eaP[j];                               \
        MLPW; QSTMT                                                           \
      }                                                                       \
    }                                                                         \
    for (; k < k1; ++k) {                                                     \
      const int sA = esrc_s[k];                                               \
      const float4 stc = st_in[(size_t)sA * 64 + lane];                       \
      const float4* hb = (const float4*)(hidb + (size_t)k * 16);              \
      const float4 g1 = hb[0], g2 = hb[1], g3 = hb[2], g4 = hb[3];            \
      const float4 ea = ea4[k];                                               \
      MLPW; QSTMT                                                             \
    }                                                                         \
  }

__global__ __launch_bounds__(256, 3) void gather_update(
    const int* __restrict__ off, const int* __restrict__ esrc_s,
    const float4* __restrict__ ea4, const float* __restrict__ hidb,
    const float4* __restrict__ st_in, const int* __restrict__ nattr,
    const float* __restrict__ Ws, const float* __restrict__ Wv,
    const float* __restrict__ Wtl, const float* __restrict__ br2l,
    const float* __restrict__ Qm,
    float4* __restrict__ st_out, float* __restrict__ xv_out, int n)
{
  __shared__ float eAx[64], eAy[64], eAz[64], eCx[64], eCy[64], eCz[64];
  __shared__ float eB[64], eD[64];
  __shared__ float oP[4][5][64];
  const int lane = threadIdx.x & 63;
  const int wid = threadIdx.x >> 6;
  const int node = blockIdx.x;

  // 16 Wr2 coefficients for this (quarter, channel) — resident in VGPRs.
  const int chg = (wid << 6) + lane;
  const float* wp = Wtl + (size_t)chg * RH;
  const float4 W0 = *(const float4*)wp;
  const float4 W1 = *(const float4*)(wp + 4);
  const float4 W2 = *(const float4*)(wp + 8);
  const float4 W3 = *(const float4*)(wp + 12);
  const float bias = br2l[chg];

  float a0 = 0.f, a1 = 0.f, a2 = 0.f;
  const int k0 = off[node], k1 = off[node + 1];
  if (k0 < k1) {
    if (wid == 0) {
      EDGE_PIPELINE({
        const float t = w * stc.x;
        a0 = fmaf(t, ea.x, a0); a1 = fmaf(t, ea.y, a1); a2 = fmaf(t, ea.z, a2);
      })
    } else if (wid == 1) {
      EDGE_PIPELINE({
        const float dt = stc.y * ea.x + stc.z * ea.y + stc.w * ea.z;
        a0 = fmaf(w, dt, a0);
      })
    } else if (wid == 2) {
      EDGE_PIPELINE({
        a0 = fmaf(w, stc.z * ea.z - stc.w * ea.y, a0);
        a1 = fmaf(w, stc.w * ea.x - stc.y * ea.z, a1);
        a2 = fmaf(w, stc.y * ea.y - stc.z * ea.x, a2);
      })
    } else {
      EDGE_PIPELINE({
        const float dt = stc.y * ea.x + stc.z * ea.y + stc.w * ea.z;
        a0 = fmaf(w, dt, a0);
      })
    }
  }
  if (wid == 0)      { eAx[lane] = a0; eAy[lane] = a1; eAz[lane] = a2; }
  else if (wid == 1) { eB[lane] = a0; }
  else if (wid == 2) { eCx[lane] = a0; eCy[lane] = a1; eCz[lane] = a2; }
  else               { eD[lane] = a0; }

  // node phase: each wave does 16 of the 64 s2 values
  const int ty = nattr[node];
  const float* WsT = Ws + (size_t)ty * 8192;
  const float* WvT = Wv + (size_t)ty * 4096;
  const float4 own = st_in[(size_t)node * 64 + lane];
  float oS1 = 0.f, oS2 = 0.f, oV0 = 0.f, oV1 = 0.f, oV2 = 0.f;
  const int s20 = wid << 4;
  #pragma unroll 4
  for (int s2 = s20; s2 < s20 + 16; ++s2) {
    const float yss = __shfl(own.x, s2, 64);
    const float b0 = __shfl(own.y, s2, 64);
    const float b1 = __shfl(own.z, s2, 64);
    const float b2 = __shfl(own.w, s2, 64);
    oS1 = fmaf(yss, WsT[s2 * 128 + lane], oS1);
    oS2 = fmaf(yss, WsT[s2 * 128 + 64 + lane], oS2);
    const float wvv = WvT[s2 * 64 + lane];
    oV0 = fmaf(b0, wvv, oV0);
    oV1 = fmaf(b1, wvv, oV1);
    oV2 = fmaf(b2, wvv, oV2);
  }
  oP[wid][0][lane] = oS1; oP[wid][1][lane] = oS2;
  oP[wid][2][lane] = oV0; oP[wid][3][lane] = oV1; oP[wid][4][lane] = oV2;
  __syncthreads();

  if (wid == 0) {
    const float inv_deg = 0.17677669529663687f;  // 1/sqrt(32)
    const float aS1 = eB[lane], aS2 = eD[lane];
    const float aV0 = eAx[lane] + eCx[lane];
    const float aV1 = eAy[lane] + eCy[lane];
    const float aV2 = eAz[lane] + eCz[lane];
    float s1 = 0.f, s2v = 0.f, v0 = 0.f, v1 = 0.f, v2 = 0.f;
    #pragma unroll
    for (int q = 0; q < 4; ++q) {
      s1 += oP[q][0][lane]; s2v += oP[q][1][lane];
      v0 += oP[q][2][lane]; v1 += oP[q][3][lane]; v2 += oP[q][4][lane];
    }
    const float outS1 = s1 + aS1 * inv_deg;
    const float outS2 = s2v + aS2 * inv_deg;
    const float sig1 = 1.f / (1.f + expf(-outS1));
    const float gate = 1.f / (1.f + expf(-outS2));
    const float ysn = own.x + HSTEP * outS1 * sig1;
    const float gf = HSTEP * gate;
    const float yvn0 = own.y + gf * (v0 + aV0 * inv_deg);
    const float yvn1 = own.z + gf * (v1 + aV1 * inv_deg);
    const float yvn2 = own.w + gf * (v2 + aV2 * inv_deg);
    st_out[(size_t)node * 64 + lane] = make_float4(ysn, yvn0, yvn1, yvn2);

    // x_v projection: butterfly reduce 6 scalars over the wave
    const float q0 = Qm[lane * 2 + 0], q1 = Qm[lane * 2 + 1];
    float pr[6] = { yvn0 * q0, yvn1 * q0, yvn2 * q0,
                    yvn0 * q1, yvn1 * q1, yvn2 * q1 };
    #pragma unroll
    for (int mm = 1; mm < 64; mm <<= 1) {
      #pragma unroll
      for (int i = 0; i < 6; ++i) pr[i] += __shfl_xor(pr[i], mm, 64);
    }
    if (lane == 0) {
      #pragma unroll
      for (int i = 0; i < 6; ++i) xv_out[(size_t)node * 6 + i] = pr[i];
    }
  }
}

// ---------------------------------------------------------------------------
extern "C" void kernel_launch(void* const* d_in, const int* in_sizes, int n_in,
                              void* d_out, int out_size, void* d_ws, size_t ws_size,
                              hipStream_t stream)
{
  const float* x     = (const float*)d_in[0];
  const int*   nattr = (const int*)d_in[2];
  const int*   esrc  = (const int*)d_in[3];
  const int*   edst  = (const int*)d_in[4];
  const float* embed = (const float*)d_in[5];
  const float* Ku    = (const float*)d_in[6];
  const float* Wss   = (const float*)d_in[7];
  const float* Wsv   = (const float*)d_in[8];
  const float* Wr1   = (const float*)d_in[9];
  const float* br1   = (const float*)d_in[10];
  const float* Wr2   = (const float*)d_in[11];
  const float* br2   = (const float*)d_in[12];
  const int n = in_sizes[0] / 6;
  const int m = in_sizes[3];

  char* p = (char*)d_ws;
  auto alloc = [&](size_t bytes) -> char* {
    char* r = p;
    p += (bytes + 255) & ~(size_t)255;
    return r;
  };
  int*    off    = (int*)alloc((size_t)(n + 1) * 4);
  int*    cursor = (int*)alloc((size_t)n * 4);
  int*    esrc_s = (int*)alloc((size_t)m * 4);
  int*    edst_s = (int*)alloc((size_t)m * 4);
  float*  Q      = (float*)alloc(128 * 4);
  float*  Ws     = (float*)alloc((size_t)LAYERS * NTYPES * 64 * 128 * 4);
  float*  Wv     = (float*)alloc((size_t)LAYERS * NTYPES * 64 * 64 * 4);
  float4* st0    = (float4*)alloc((size_t)n * 64 * 16);
  float4* st1    = (float4*)alloc((size_t)n * 64 * 16);
  float*  xvb    = (float*)alloc((size_t)n * 6 * 4);
  float4* ea4    = (float4*)alloc((size_t)m * 16);
  float*  hidb   = (float*)alloc((size_t)m * 16 * 4);
  float*  Wt     = (float*)alloc((size_t)LAYERS * 4096 * 4);

  const int total_s = LAYERS * NTYPES * 64 * 128;
  const int total_v = LAYERS * NTYPES * 64 * 64;

  qr_kernel<<<1, 64, 0, stream>>>(Ku, Q);
  init_state<<<(n * 64 + 255) / 256, 256, 0, stream>>>(x, Q, st0, cursor, n);
  hist_kernel<<<(m + 255) / 256, 256, 0, stream>>>(edst, cursor, m);
  scan_kernel<<<1, 1024, 0, stream>>>(cursor, off, n);
  scatter_kernel<<<(m + 255) / 256, 256, 0, stream>>>(esrc, edst, cursor, esrc_s, edst_s, m);
  type_weights<<<(total_s + total_v + 255) / 256, 256, 0, stream>>>(
      embed, Wss, Wsv, Ws, Wv, total_s, total_v);
  transpose_wr2<<<2, 256, 0, stream>>>(Wr2, Wt);

  const float* xv_cur = x;
  const float4* st_cur = st0;
  float4* st_nxt = st1;
  for (int l = 0; l < LAYERS; ++l) {
    edge_geom<<<(m + 255) / 256, 256, 0, stream>>>(
        xv_cur, esrc_s, edst_s, Wr1 + l * NB * RH, br1 + l * RH, ea4, hidb, m);
    float* xv_out = (l == LAYERS - 1) ? (float*)d_out : xvb;
    gather_update<<<n, 256, 0, stream>>>(
        off, esrc_s, ea4, hidb, st_cur, nattr,
        Ws + (size_t)l * NTYPES * 8192, Wv + (size_t)l * NTYPES * 4096,
        Wt + (size_t)l * 4096, br2 + l * 256, Q,
        st_nxt, xv_out, n);
    xv_cur = xv_out;
    float4* ts = (float4*)st_cur; st_cur = st_nxt; st_nxt = ts;
  }
}